// Round 1
// baseline (589.389 us; speedup 1.0000x reference)
//
#include <hip/hip_runtime.h>
#include <cmath>

#define DM   1024
#define HDS  16
#define DH   64
#define DMLP 4096
#define TSEQ 2048
#define NROW 4096   // B*T = 2*2048

typedef short bf16x8 __attribute__((ext_vector_type(8)));
typedef float f32x4 __attribute__((ext_vector_type(4)));

__device__ __forceinline__ unsigned short f2bf(float f) {
  union { float f; unsigned u; } v; v.f = f;
  unsigned r = v.u + 0x7fffu + ((v.u >> 16) & 1u);
  return (unsigned short)(r >> 16);
}

__device__ __forceinline__ void gload_lds16(const void* g, void* l) {
  __builtin_amdgcn_global_load_lds(
      (const __attribute__((address_space(1))) unsigned int*)g,
      (__attribute__((address_space(3))) unsigned int*)l, 16, 0, 0);
}

// ---------- transpose fp32 [K][N] -> bf16 [N][K] ----------
__global__ __launch_bounds__(256) void tr_kernel(const float* __restrict__ in,
                                                 unsigned short* __restrict__ out,
                                                 int K, int N) {
  __shared__ unsigned short tile[32][33];
  int n0 = blockIdx.x * 32, k0 = blockIdx.y * 32;
  int tx = threadIdx.x & 31, ty = threadIdx.x >> 5;
#pragma unroll
  for (int j = 0; j < 4; ++j) {
    int k = ty + j * 8;
    tile[k][tx] = f2bf(in[(size_t)(k0 + k) * N + n0 + tx]);
  }
  __syncthreads();
#pragma unroll
  for (int j = 0; j < 4; ++j) {
    int n = ty + j * 8;
    out[(size_t)(n0 + n) * K + k0 + tx] = tile[tx][n];
  }
}

__global__ void concat3_kernel(const float* __restrict__ a, const float* __restrict__ b,
                               const float* __restrict__ c, float* __restrict__ out, int n) {
  int i = blockIdx.x * 256 + threadIdx.x;
  if (i < n) { out[i] = a[i]; out[n + i] = b[i]; out[2 * n + i] = c[i]; }
}

// ---------- rmsnorm fp32 [NROW][DM] -> bf16 ----------
__global__ __launch_bounds__(256) void rmsnorm_kernel(const float* __restrict__ x,
                                                      const float* __restrict__ w,
                                                      unsigned short* __restrict__ out) {
  int row = blockIdx.x;
  int t = threadIdx.x;
  const float4* xr = (const float4*)(x + (size_t)row * DM);
  float4 v = xr[t];
  float ss = v.x * v.x + v.y * v.y + v.z * v.z + v.w * v.w;
#pragma unroll
  for (int m = 1; m < 64; m <<= 1) ss += __shfl_xor(ss, m, 64);
  __shared__ float sred[4];
  if ((t & 63) == 0) sred[t >> 6] = ss;
  __syncthreads();
  ss = sred[0] + sred[1] + sred[2] + sred[3];
  float norm = rsqrtf(ss * (1.0f / DM) + 1e-6f);
  float4 wv = ((const float4*)w)[t];
  ushort4 o;
  o.x = f2bf(v.x * norm * wv.x);
  o.y = f2bf(v.y * norm * wv.y);
  o.z = f2bf(v.z * norm * wv.z);
  o.w = f2bf(v.w * norm * wv.w);
  ((ushort4*)out)[(size_t)row * (DM / 4) + t] = o;
}

// ---------- GEMM: C[M][N] = A[M][K] * BT[N][K]^T + epilogue ----------
// EPI: 0 = +bias -> bf16 ; 1 = +bias + res -> f32 ; 2 = +bias, exact gelu -> bf16
template <int EPI>
__global__ __launch_bounds__(256) void gemm_bt(const unsigned short* __restrict__ A,
                                               const unsigned short* __restrict__ BT,
                                               const float* __restrict__ bias,
                                               const float* __restrict__ res,
                                               void* __restrict__ outp,
                                               int M, int N, int K) {
  __shared__ alignas(16) unsigned short As[128 * 32];
  __shared__ alignas(16) unsigned short Bs[128 * 32];
  int tid = threadIdx.x;
  int w = tid >> 6, l = tid & 63;
  int m0 = blockIdx.y * 128, n0 = blockIdx.x * 128;
  int wr = w >> 1, wc = w & 1;
  f32x4 acc[4][4];
#pragma unroll
  for (int i = 0; i < 4; ++i)
#pragma unroll
    for (int j = 0; j < 4; ++j)
#pragma unroll
      for (int e = 0; e < 4; ++e) acc[i][j][e] = 0.0f;

  int nk = K >> 5;
  int arow = tid >> 2, aslot = tid & 3;  // 64 rows per half-tile, 4x16B slots per row
  for (int kt = 0; kt < nk; ++kt) {
    __syncthreads();
#pragma unroll
    for (int i = 0; i < 2; ++i) {
      int row = i * 64 + arow;
      gload_lds16(A + (size_t)(m0 + row) * K + (size_t)kt * 32 + aslot * 8,
                  (char*)As + i * 4096 + w * 1024);
      gload_lds16(BT + (size_t)(n0 + row) * K + (size_t)kt * 32 + aslot * 8,
                  (char*)Bs + i * 4096 + w * 1024);
    }
    __syncthreads();
    bf16x8 af[4], bfr[4];
#pragma unroll
    for (int mt = 0; mt < 4; ++mt)
      af[mt] = *(const bf16x8*)((const char*)As +
                (size_t)(wr * 64 + mt * 16 + (l & 15)) * 64 + (l >> 4) * 16);
#pragma unroll
    for (int nt = 0; nt < 4; ++nt)
      bfr[nt] = *(const bf16x8*)((const char*)Bs +
                 (size_t)(wc * 64 + nt * 16 + (l & 15)) * 64 + (l >> 4) * 16);
#pragma unroll
    for (int mt = 0; mt < 4; ++mt)
#pragma unroll
      for (int nt = 0; nt < 4; ++nt)
        acc[mt][nt] = __builtin_amdgcn_mfma_f32_16x16x32_bf16(af[mt], bfr[nt], acc[mt][nt], 0, 0, 0);
  }

  int g = l >> 4, c = l & 15;
#pragma unroll
  for (int mt = 0; mt < 4; ++mt) {
#pragma unroll
    for (int nt = 0; nt < 4; ++nt) {
#pragma unroll
      for (int r = 0; r < 4; ++r) {
        int m = m0 + wr * 64 + mt * 16 + g * 4 + r;
        int n = n0 + wc * 64 + nt * 16 + c;
        float v = acc[mt][nt][r] + bias[n];
        if (EPI == 2) v = 0.5f * v * (1.0f + erff(v * 0.70710678118654752f));
        if (EPI == 1) {
          v += res[(size_t)m * N + n];
          ((float*)outp)[(size_t)m * N + n] = v;
        } else {
          ((unsigned short*)outp)[(size_t)m * N + n] = f2bf(v);
        }
      }
    }
  }
}

// ---------- causal flash attention ----------
// qkv bf16 [NROW][3072]: q | k | v each [.,1024], head h at col h*64
// block: 4 waves x 16 q-rows = 64 q-rows, one (b,h); KV tiles of 32
__global__ __launch_bounds__(256) void attn_kernel(const unsigned short* __restrict__ qkv,
                                                   unsigned short* __restrict__ attn_out) {
  __shared__ alignas(16) unsigned short Ks[32 * 64];    // [k][d]
  __shared__ alignas(16) unsigned short VTs[64 * 32];   // [d][k]
  __shared__ alignas(16) unsigned short Ps[4][16 * 32]; // per-wave P tile
  int tid = threadIdx.x, w = tid >> 6, l = tid & 63;
  int g = l >> 4, c = l & 15;
  int bid = blockIdx.x;
  int qb = bid & 31, bh = bid >> 5, b = bh >> 4, h = bh & 15;
  int q0 = qb * 64;

  bf16x8 qf0, qf1;
  {
    size_t qrow = (size_t)b * TSEQ + q0 + w * 16 + c;
    const unsigned short* qp = qkv + qrow * 3072 + h * 64 + g * 8;
    qf0 = *(const bf16x8*)qp;
    qf1 = *(const bf16x8*)(qp + 32);
  }
  f32x4 o[4];
  float mrow[4], lrow[4];
#pragma unroll
  for (int dc = 0; dc < 4; ++dc)
#pragma unroll
    for (int e = 0; e < 4; ++e) o[dc][e] = 0.0f;
#pragma unroll
  for (int r = 0; r < 4; ++r) { mrow[r] = -1e30f; lrow[r] = 0.0f; }

  int qmax = q0 + w * 16 + 15;
  int nt = (q0 + 64) >> 5;
  int krow = tid >> 3, kslot = tid & 7;
  for (int kt = 0; kt < nt; ++kt) {
    int k0 = kt * 32;
    // stage K tile [32][64] linear via global_load_lds
    gload_lds16(qkv + (size_t)(b * TSEQ + k0 + krow) * 3072 + 1024 + h * 64 + kslot * 8,
                (char*)Ks + w * 1024);
    // stage V transposed [d][k] via registers
    {
      bf16x8 vv = *(const bf16x8*)(qkv + (size_t)(b * TSEQ + k0 + krow) * 3072 + 2048 + h * 64 + kslot * 8);
#pragma unroll
      for (int j = 0; j < 8; ++j)
        VTs[(kslot * 8 + j) * 32 + krow] = (unsigned short)vv[j];
    }
    __syncthreads();
    if (k0 <= qmax) {
      // S tile [16 q][32 k]
      f32x4 s[2];
#pragma unroll
      for (int ni = 0; ni < 2; ++ni) {
        bf16x8 kfa = *(const bf16x8*)((const char*)Ks + (ni * 16 + c) * 128 + g * 16);
        bf16x8 kfb = *(const bf16x8*)((const char*)Ks + (ni * 16 + c) * 128 + 64 + g * 16);
        f32x4 t;
#pragma unroll
        for (int e = 0; e < 4; ++e) t[e] = 0.0f;
        t = __builtin_amdgcn_mfma_f32_16x16x32_bf16(qf0, kfa, t, 0, 0, 0);
        t = __builtin_amdgcn_mfma_f32_16x16x32_bf16(qf1, kfb, t, 0, 0, 0);
        s[ni] = t;
      }
      float pm[2][4];
#pragma unroll
      for (int ni = 0; ni < 2; ++ni)
#pragma unroll
        for (int r = 0; r < 4; ++r) {
          int kg = k0 + ni * 16 + c;
          int qg = q0 + w * 16 + g * 4 + r;
          float v = s[ni][r] * 0.125f;  // 1/sqrt(64)
          pm[ni][r] = (kg <= qg) ? v : -1e30f;
        }
#pragma unroll
      for (int r = 0; r < 4; ++r) {
        float mx = fmaxf(pm[0][r], pm[1][r]);
        mx = fmaxf(mx, __shfl_xor(mx, 1, 64));
        mx = fmaxf(mx, __shfl_xor(mx, 2, 64));
        mx = fmaxf(mx, __shfl_xor(mx, 4, 64));
        mx = fmaxf(mx, __shfl_xor(mx, 8, 64));
        float mnew = fmaxf(mrow[r], mx);
        float scale = __expf(mrow[r] - mnew);
        float p0 = __expf(pm[0][r] - mnew);
        float p1 = __expf(pm[1][r] - mnew);
        float rs = p0 + p1;
        rs += __shfl_xor(rs, 1, 64);
        rs += __shfl_xor(rs, 2, 64);
        rs += __shfl_xor(rs, 4, 64);
        rs += __shfl_xor(rs, 8, 64);
        lrow[r] = lrow[r] * scale + rs;
        mrow[r] = mnew;
#pragma unroll
        for (int dc = 0; dc < 4; ++dc) o[dc][r] *= scale;
        Ps[w][(g * 4 + r) * 32 + c] = f2bf(p0);
        Ps[w][(g * 4 + r) * 32 + 16 + c] = f2bf(p1);
      }
      asm volatile("s_waitcnt lgkmcnt(0)" ::: "memory");
      // PV: A = P [16][32], B = V^T -> O [16 q][64 d]
      bf16x8 pf = *(const bf16x8*)((const char*)Ps[w] + c * 64 + g * 16);
#pragma unroll
      for (int dc = 0; dc < 4; ++dc) {
        bf16x8 vf = *(const bf16x8*)((const char*)VTs + (dc * 16 + c) * 64 + g * 16);
        o[dc] = __builtin_amdgcn_mfma_f32_16x16x32_bf16(pf, vf, o[dc], 0, 0, 0);
      }
    }
    __syncthreads();
  }
#pragma unroll
  for (int r = 0; r < 4; ++r) {
    float inv = 1.0f / lrow[r];
    size_t row = (size_t)b * TSEQ + q0 + w * 16 + g * 4 + r;
    unsigned short* op = attn_out + row * 1024 + h * 64 + c;
#pragma unroll
    for (int dc = 0; dc < 4; ++dc) op[dc * 16] = f2bf(o[dc][r] * inv);
  }
}

extern "C" void kernel_launch(void* const* d_in, const int* in_sizes, int n_in,
                              void* d_out, int out_size, void* d_ws, size_t ws_size,
                              hipStream_t stream) {
  const float* x    = (const float*)d_in[0];
  const float* ln1w = (const float*)d_in[1];
  const float* ln2w = (const float*)d_in[2];
  const float* Wq   = (const float*)d_in[3];
  const float* bq   = (const float*)d_in[4];
  const float* Wk   = (const float*)d_in[5];
  const float* bk   = (const float*)d_in[6];
  const float* Wv   = (const float*)d_in[7];
  const float* bv   = (const float*)d_in[8];
  const float* Wo   = (const float*)d_in[9];
  const float* bo   = (const float*)d_in[10];
  const float* Wup  = (const float*)d_in[11];
  const float* bup  = (const float*)d_in[12];
  const float* Wdn  = (const float*)d_in[13];
  const float* bdn  = (const float*)d_in[14];

  char* ws = (char*)d_ws;
  unsigned short* xn1   = (unsigned short*)(ws + 0);              // 8 MB  [4096][1024] bf16
  unsigned short* qkv   = (unsigned short*)(ws + (8ull << 20));   // 24 MB [4096][3072] bf16
  unsigned short* gbuf  = (unsigned short*)(ws + 0);              // 32 MB, aliases xn1+qkv (both dead)
  unsigned short* attn  = (unsigned short*)(ws + (32ull << 20));  // 8 MB  [4096][1024] bf16
  float*          x2    = (float*)(ws + (40ull << 20));           // 16 MB [4096][1024] f32
  unsigned short* h2    = (unsigned short*)(ws + (56ull << 20));  // 8 MB
  unsigned short* WqkvT = (unsigned short*)(ws + (64ull << 20));  // 6 MB  [3072][1024]
  unsigned short* WoT   = (unsigned short*)(ws + (70ull << 20));  // 2 MB  [1024][1024]
  unsigned short* WupT  = (unsigned short*)(ws + (72ull << 20));  // 8 MB  [4096][1024]
  unsigned short* WdnT  = (unsigned short*)(ws + (80ull << 20));  // 8 MB  [1024][4096]
  float*          bqkv  = (float*)(ws + (88ull << 20));           // 12 KB [3072]

  dim3 blk(256);
  // weight transposes (fp32 -> bf16 W^T)
  tr_kernel<<<dim3(32, 32), blk, 0, stream>>>(Wq, WqkvT, 1024, 1024);
  tr_kernel<<<dim3(32, 32), blk, 0, stream>>>(Wk, WqkvT + 1024 * 1024, 1024, 1024);
  tr_kernel<<<dim3(32, 32), blk, 0, stream>>>(Wv, WqkvT + 2 * 1024 * 1024, 1024, 1024);
  tr_kernel<<<dim3(32, 32), blk, 0, stream>>>(Wo, WoT, 1024, 1024);
  tr_kernel<<<dim3(128, 32), blk, 0, stream>>>(Wup, WupT, 1024, 4096);
  tr_kernel<<<dim3(32, 128), blk, 0, stream>>>(Wdn, WdnT, 4096, 1024);
  concat3_kernel<<<dim3(4), blk, 0, stream>>>(bq, bk, bv, bqkv, 1024);

  // x -> rmsnorm -> qkv
  rmsnorm_kernel<<<dim3(NROW), blk, 0, stream>>>(x, ln1w, xn1);
  gemm_bt<0><<<dim3(24, 32), blk, 0, stream>>>(xn1, WqkvT, bqkv, nullptr, qkv, NROW, 3072, 1024);

  // attention
  attn_kernel<<<dim3(1024), blk, 0, stream>>>(qkv, attn);

  // x2 = x + attn @ Wo + bo
  gemm_bt<1><<<dim3(8, 32), blk, 0, stream>>>(attn, WoT, bo, x, x2, NROW, 1024, 1024);

  // mlp
  rmsnorm_kernel<<<dim3(NROW), blk, 0, stream>>>(x2, ln2w, h2);
  gemm_bt<2><<<dim3(32, 32), blk, 0, stream>>>(h2, WupT, bup, nullptr, gbuf, NROW, 4096, 1024);
  gemm_bt<1><<<dim3(8, 32), blk, 0, stream>>>(gbuf, WdnT, bdn, x2, d_out, NROW, 1024, 4096);
}

// Round 2
// 492.577 us; speedup vs baseline: 1.1965x; 1.1965x over previous
//
#include <hip/hip_runtime.h>
#include <cmath>

#define DM   1024
#define HDS  16
#define DH   64
#define DMLP 4096
#define TSEQ 2048
#define NROW 4096   // B*T = 2*2048

typedef short bf16x8 __attribute__((ext_vector_type(8)));
typedef float f32x4 __attribute__((ext_vector_type(4)));

__device__ __forceinline__ unsigned short f2bf(float f) {
  union { float f; unsigned u; } v; v.f = f;
  unsigned r = v.u + 0x7fffu + ((v.u >> 16) & 1u);
  return (unsigned short)(r >> 16);
}

__device__ __forceinline__ void gload_lds16(const void* g, void* l) {
  __builtin_amdgcn_global_load_lds(
      (const __attribute__((address_space(1))) unsigned int*)g,
      (__attribute__((address_space(3))) unsigned int*)l, 16, 0, 0);
}

// ---------- transpose fp32 [K][N] -> bf16 [N][K] ----------
__global__ __launch_bounds__(256) void tr_kernel(const float* __restrict__ in,
                                                 unsigned short* __restrict__ out,
                                                 int K, int N) {
  __shared__ unsigned short tile[32][33];
  int n0 = blockIdx.x * 32, k0 = blockIdx.y * 32;
  int tx = threadIdx.x & 31, ty = threadIdx.x >> 5;
#pragma unroll
  for (int j = 0; j < 4; ++j) {
    int k = ty + j * 8;
    tile[k][tx] = f2bf(in[(size_t)(k0 + k) * N + n0 + tx]);
  }
  __syncthreads();
#pragma unroll
  for (int j = 0; j < 4; ++j) {
    int n = ty + j * 8;
    out[(size_t)(n0 + n) * K + k0 + tx] = tile[tx][n];
  }
}

__global__ void concat3_kernel(const float* __restrict__ a, const float* __restrict__ b,
                               const float* __restrict__ c, float* __restrict__ out, int n) {
  int i = blockIdx.x * 256 + threadIdx.x;
  if (i < n) { out[i] = a[i]; out[n + i] = b[i]; out[2 * n + i] = c[i]; }
}

// ---------- rmsnorm fp32 [NROW][DM] -> bf16 ----------
__global__ __launch_bounds__(256) void rmsnorm_kernel(const float* __restrict__ x,
                                                      const float* __restrict__ w,
                                                      unsigned short* __restrict__ out) {
  int row = blockIdx.x;
  int t = threadIdx.x;
  const float4* xr = (const float4*)(x + (size_t)row * DM);
  float4 v = xr[t];
  float ss = v.x * v.x + v.y * v.y + v.z * v.z + v.w * v.w;
#pragma unroll
  for (int m = 1; m < 64; m <<= 1) ss += __shfl_xor(ss, m, 64);
  __shared__ float sred[4];
  if ((t & 63) == 0) sred[t >> 6] = ss;
  __syncthreads();
  ss = sred[0] + sred[1] + sred[2] + sred[3];
  float norm = rsqrtf(ss * (1.0f / DM) + 1e-6f);
  float4 wv = ((const float4*)w)[t];
  ushort4 o;
  o.x = f2bf(v.x * norm * wv.x);
  o.y = f2bf(v.y * norm * wv.y);
  o.z = f2bf(v.z * norm * wv.z);
  o.w = f2bf(v.w * norm * wv.w);
  ((ushort4*)out)[(size_t)row * (DM / 4) + t] = o;
}

// ---------- GEMM: C[M][N] = A[M][K] * BT[N][K]^T + epilogue ----------
// EPI: 0 = +bias -> bf16 ; 1 = +bias + res -> f32 ; 2 = +bias, exact gelu -> bf16
template <int EPI>
__global__ __launch_bounds__(256) void gemm_bt(const unsigned short* __restrict__ A,
                                               const unsigned short* __restrict__ BT,
                                               const float* __restrict__ bias,
                                               const float* __restrict__ res,
                                               void* __restrict__ outp,
                                               int M, int N, int K) {
  __shared__ alignas(16) unsigned short As[128 * 32];
  __shared__ alignas(16) unsigned short Bs[128 * 32];
  int tid = threadIdx.x;
  int w = tid >> 6, l = tid & 63;
  int m0 = blockIdx.y * 128, n0 = blockIdx.x * 128;
  int wr = w >> 1, wc = w & 1;
  f32x4 acc[4][4];
#pragma unroll
  for (int i = 0; i < 4; ++i)
#pragma unroll
    for (int j = 0; j < 4; ++j)
#pragma unroll
      for (int e = 0; e < 4; ++e) acc[i][j][e] = 0.0f;

  int nk = K >> 5;
  int arow = tid >> 2, aslot = tid & 3;  // 64 rows per half-tile, 4x16B slots per row
  for (int kt = 0; kt < nk; ++kt) {
    __syncthreads();
#pragma unroll
    for (int i = 0; i < 2; ++i) {
      int row = i * 64 + arow;
      gload_lds16(A + (size_t)(m0 + row) * K + (size_t)kt * 32 + aslot * 8,
                  (char*)As + i * 4096 + w * 1024);
      gload_lds16(BT + (size_t)(n0 + row) * K + (size_t)kt * 32 + aslot * 8,
                  (char*)Bs + i * 4096 + w * 1024);
    }
    __syncthreads();
    bf16x8 af[4], bfr[4];
#pragma unroll
    for (int mt = 0; mt < 4; ++mt)
      af[mt] = *(const bf16x8*)((const char*)As +
                (size_t)(wr * 64 + mt * 16 + (l & 15)) * 64 + (l >> 4) * 16);
#pragma unroll
    for (int nt = 0; nt < 4; ++nt)
      bfr[nt] = *(const bf16x8*)((const char*)Bs +
                 (size_t)(wc * 64 + nt * 16 + (l & 15)) * 64 + (l >> 4) * 16);
#pragma unroll
    for (int mt = 0; mt < 4; ++mt)
#pragma unroll
      for (int nt = 0; nt < 4; ++nt)
        acc[mt][nt] = __builtin_amdgcn_mfma_f32_16x16x32_bf16(af[mt], bfr[nt], acc[mt][nt], 0, 0, 0);
  }

  int g = l >> 4, c = l & 15;
#pragma unroll
  for (int mt = 0; mt < 4; ++mt) {
#pragma unroll
    for (int nt = 0; nt < 4; ++nt) {
#pragma unroll
      for (int r = 0; r < 4; ++r) {
        int m = m0 + wr * 64 + mt * 16 + g * 4 + r;
        int n = n0 + wc * 64 + nt * 16 + c;
        float v = acc[mt][nt][r] + bias[n];
        if (EPI == 2) v = 0.5f * v * (1.0f + erff(v * 0.70710678118654752f));
        if (EPI == 1) {
          v += res[(size_t)m * N + n];
          ((float*)outp)[(size_t)m * N + n] = v;
        } else {
          ((unsigned short*)outp)[(size_t)m * N + n] = f2bf(v);
        }
      }
    }
  }
}

// ---------- V transpose: qkv v-part -> VT [bh][64 d][2048 t] bf16 ----------
__global__ __launch_bounds__(256) void vtr_kernel(const unsigned short* __restrict__ qkv,
                                                  unsigned short* __restrict__ vt) {
  __shared__ unsigned short tile[64][72];
  int bh = blockIdx.y, t0 = blockIdx.x * 64;
  int b = bh >> 4, h = bh & 15;
  int r = threadIdx.x >> 3, sl = threadIdx.x & 7;
#pragma unroll
  for (int half = 0; half < 2; ++half) {
    int rr = r + half * 32;
    bf16x8 v = *(const bf16x8*)(qkv + (size_t)(b * TSEQ + t0 + rr) * 3072 + 2048 + h * 64 + sl * 8);
    *(bf16x8*)&tile[rr][sl * 8] = v;  // row stride 144B (16B-aligned)
  }
  __syncthreads();
#pragma unroll
  for (int half = 0; half < 2; ++half) {
    int d = r + half * 32;
    bf16x8 o;
#pragma unroll
    for (int j = 0; j < 8; ++j) o[j] = (short)tile[sl * 8 + j][d];
    *(bf16x8*)(vt + ((size_t)bh * 64 + d) * TSEQ + t0 + sl * 8) = o;
  }
}

// ---------- causal flash attention v2 ----------
// 4 waves x 32 q-rows = 128 q/block; KVBLK=64; K/VT/P LDS XOR-swizzled;
// double-buffered reg staging, one barrier per KV tile.
__global__ __launch_bounds__(256) void attn_kernel(const unsigned short* __restrict__ qkv,
                                                   const unsigned short* __restrict__ vt,
                                                   unsigned short* __restrict__ attn_out) {
  __shared__ alignas(16) unsigned short Ks[2][64 * 64];  // [k][d] swz
  __shared__ alignas(16) unsigned short Vs[2][64 * 64];  // [d][k] swz
  __shared__ alignas(16) unsigned short Ps[4][32 * 64];  // per-wave [q][k] swz
  int tid = threadIdx.x, w = tid >> 6, l = tid & 63, g = l >> 4, c = l & 15;
  int bid = blockIdx.x;
  int qb = 15 - (bid & 15);             // heavy blocks dispatch first
  int bh = bid >> 4, b = bh >> 4, h = bh & 15;
  int q0 = qb * 128;
  int qw = q0 + w * 32;

  // Q fragments in registers: rows qw + mt*16 + c, d-slices s*32 + g*8
  bf16x8 qf[2][2];
#pragma unroll
  for (int mt = 0; mt < 2; ++mt)
#pragma unroll
    for (int s = 0; s < 2; ++s)
      qf[mt][s] = *(const bf16x8*)(qkv + (size_t)(b * TSEQ + qw + mt * 16 + c) * 3072 +
                                   h * 64 + s * 32 + g * 8);

  f32x4 o[2][4];
  float mrow[2][4], lrow[2][4];
#pragma unroll
  for (int mt = 0; mt < 2; ++mt)
#pragma unroll
    for (int dc = 0; dc < 4; ++dc)
#pragma unroll
      for (int e = 0; e < 4; ++e) o[mt][dc][e] = 0.0f;
#pragma unroll
  for (int mt = 0; mt < 2; ++mt)
#pragma unroll
    for (int r = 0; r < 4; ++r) { mrow[mt][r] = -1e30f; lrow[mt][r] = 0.0f; }

  int ntile = (q0 + 128) >> 6;
  int sr = tid >> 3, ss = tid & 7;  // staging: 32 rows x 8 slots, 2 halves
  bf16x8 kreg[2], vreg[2];

#define LOADT(K0)                                                                       \
  {                                                                                     \
    _Pragma("unroll") for (int hf = 0; hf < 2; ++hf) {                                  \
      int rr = sr + hf * 32;                                                            \
      kreg[hf] = *(const bf16x8*)(qkv + (size_t)(b * TSEQ + (K0) + rr) * 3072 + 1024 +  \
                                  h * 64 + ss * 8);                                     \
      vreg[hf] = *(const bf16x8*)(vt + ((size_t)bh * 64 + rr) * TSEQ + (K0) + ss * 8);  \
    }                                                                                   \
  }
#define WRITET(BUF)                                                                     \
  {                                                                                     \
    _Pragma("unroll") for (int hf = 0; hf < 2; ++hf) {                                  \
      int rr = sr + hf * 32;                                                            \
      unsigned off = (unsigned)(rr * 128 + ss * 16) ^ (unsigned)((rr & 7) << 4);        \
      *(bf16x8*)((char*)Ks[BUF] + off) = kreg[hf];                                      \
      *(bf16x8*)((char*)Vs[BUF] + off) = vreg[hf];                                      \
    }                                                                                   \
  }

  LOADT(0);
  WRITET(0);
  __syncthreads();

  for (int t = 0; t < ntile; ++t) {
    int k0 = t << 6, cur = t & 1;
    if (t + 1 < ntile) LOADT((t + 1) << 6);

    if (k0 <= qw + 31) {
      const char* Kb = (const char*)Ks[cur];
      const char* Vb = (const char*)Vs[cur];
      // S[2mt][4ni] = Q x K^T over d=64 (2 mfma steps)
      f32x4 s[2][4];
#pragma unroll
      for (int ni = 0; ni < 4; ++ni) {
        int krow = ni * 16 + c;
        unsigned swz = (unsigned)((c & 7) << 4);
        bf16x8 kf0 = *(const bf16x8*)(Kb + (((unsigned)(krow * 128) + g * 16) ^ swz));
        bf16x8 kf1 = *(const bf16x8*)(Kb + (((unsigned)(krow * 128) + 64 + g * 16) ^ swz));
#pragma unroll
        for (int mt = 0; mt < 2; ++mt) {
          f32x4 acc;
#pragma unroll
          for (int e = 0; e < 4; ++e) acc[e] = 0.0f;
          acc = __builtin_amdgcn_mfma_f32_16x16x32_bf16(qf[mt][0], kf0, acc, 0, 0, 0);
          acc = __builtin_amdgcn_mfma_f32_16x16x32_bf16(qf[mt][1], kf1, acc, 0, 0, 0);
          s[mt][ni] = acc;
        }
      }
      bool full = (k0 + 63 <= qw);  // no masking needed for any row of this wave
#pragma unroll
      for (int mt = 0; mt < 2; ++mt) {
#pragma unroll
        for (int r = 0; r < 4; ++r) {
          int qg = qw + mt * 16 + g * 4 + r;
          float pm[4];
#pragma unroll
          for (int ni = 0; ni < 4; ++ni) {
            float v = s[mt][ni][r] * 0.125f;
            if (!full) {
              int kg = k0 + ni * 16 + c;
              v = (kg <= qg) ? v : -1e30f;
            }
            pm[ni] = v;
          }
          float mx = fmaxf(fmaxf(pm[0], pm[1]), fmaxf(pm[2], pm[3]));
          mx = fmaxf(mx, __shfl_xor(mx, 1, 64));
          mx = fmaxf(mx, __shfl_xor(mx, 2, 64));
          mx = fmaxf(mx, __shfl_xor(mx, 4, 64));
          mx = fmaxf(mx, __shfl_xor(mx, 8, 64));
          float mnew = fmaxf(mrow[mt][r], mx);
          float scale = __expf(mrow[mt][r] - mnew);
          float p[4], rs = 0.0f;
#pragma unroll
          for (int ni = 0; ni < 4; ++ni) { p[ni] = __expf(pm[ni] - mnew); rs += p[ni]; }
          rs += __shfl_xor(rs, 1, 64);
          rs += __shfl_xor(rs, 2, 64);
          rs += __shfl_xor(rs, 4, 64);
          rs += __shfl_xor(rs, 8, 64);
          lrow[mt][r] = lrow[mt][r] * scale + rs;
          mrow[mt][r] = mnew;
#pragma unroll
          for (int dc = 0; dc < 4; ++dc) o[mt][dc][r] *= scale;
          int prow = mt * 16 + g * 4 + r;
          unsigned pswz = (unsigned)((prow & 7) << 4);
#pragma unroll
          for (int ni = 0; ni < 4; ++ni)
            *(unsigned short*)((char*)Ps[w] +
                               (((unsigned)(prow * 128 + (ni * 16 + c) * 2)) ^ pswz)) =
                f2bf(p[ni]);
        }
      }
      asm volatile("s_waitcnt lgkmcnt(0)" ::: "memory");
      // PV: O[32q][64d] += P[32q][64k] x V[64k][64d]
      unsigned swz = (unsigned)((c & 7) << 4);
#pragma unroll
      for (int kc = 0; kc < 2; ++kc) {
        bf16x8 pf[2];
#pragma unroll
        for (int mt = 0; mt < 2; ++mt)
          pf[mt] = *(const bf16x8*)((const char*)Ps[w] +
                    (((unsigned)((mt * 16 + c) * 128 + kc * 64 + g * 16)) ^ swz));
#pragma unroll
        for (int dc = 0; dc < 4; ++dc) {
          bf16x8 vf = *(const bf16x8*)(Vb +
                       (((unsigned)((dc * 16 + c) * 128 + kc * 64 + g * 16)) ^ swz));
#pragma unroll
          for (int mt = 0; mt < 2; ++mt)
            o[mt][dc] = __builtin_amdgcn_mfma_f32_16x16x32_bf16(pf[mt], vf, o[mt][dc], 0, 0, 0);
        }
      }
    }

    if (t + 1 < ntile) {
      WRITET(cur ^ 1);
      __syncthreads();
    }
  }

#pragma unroll
  for (int mt = 0; mt < 2; ++mt) {
#pragma unroll
    for (int r = 0; r < 4; ++r) {
      float inv = 1.0f / lrow[mt][r];
      size_t row = (size_t)b * TSEQ + qw + mt * 16 + g * 4 + r;
      unsigned short* op = attn_out + row * 1024 + h * 64 + c;
#pragma unroll
      for (int dc = 0; dc < 4; ++dc) op[dc * 16] = f2bf(o[mt][dc][r] * inv);
    }
  }
#undef LOADT
#undef WRITET
}

extern "C" void kernel_launch(void* const* d_in, const int* in_sizes, int n_in,
                              void* d_out, int out_size, void* d_ws, size_t ws_size,
                              hipStream_t stream) {
  const float* x    = (const float*)d_in[0];
  const float* ln1w = (const float*)d_in[1];
  const float* ln2w = (const float*)d_in[2];
  const float* Wq   = (const float*)d_in[3];
  const float* bq   = (const float*)d_in[4];
  const float* Wk   = (const float*)d_in[5];
  const float* bk   = (const float*)d_in[6];
  const float* Wv   = (const float*)d_in[7];
  const float* bv   = (const float*)d_in[8];
  const float* Wo   = (const float*)d_in[9];
  const float* bo   = (const float*)d_in[10];
  const float* Wup  = (const float*)d_in[11];
  const float* bup  = (const float*)d_in[12];
  const float* Wdn  = (const float*)d_in[13];
  const float* bdn  = (const float*)d_in[14];

  char* ws = (char*)d_ws;
  unsigned short* xn1   = (unsigned short*)(ws + 0);              // 8 MB [4096][1024] bf16
  unsigned short* vtb   = (unsigned short*)(ws + 0);              // 8 MB [32][64][2048] bf16 (aliases xn1, dead by then)
  unsigned short* qkv   = (unsigned short*)(ws + (8ull << 20));   // 24 MB [4096][3072] bf16
  unsigned short* gbuf  = (unsigned short*)(ws + 0);              // 32 MB, aliases vtb+qkv (both dead)
  unsigned short* attn  = (unsigned short*)(ws + (32ull << 20));  // 8 MB [4096][1024] bf16
  float*          x2    = (float*)(ws + (40ull << 20));           // 16 MB [4096][1024] f32
  unsigned short* h2    = (unsigned short*)(ws + (56ull << 20));  // 8 MB
  unsigned short* WqkvT = (unsigned short*)(ws + (64ull << 20));  // 6 MB [3072][1024]
  unsigned short* WoT   = (unsigned short*)(ws + (70ull << 20));  // 2 MB [1024][1024]
  unsigned short* WupT  = (unsigned short*)(ws + (72ull << 20));  // 8 MB [4096][1024]
  unsigned short* WdnT  = (unsigned short*)(ws + (80ull << 20));  // 8 MB [1024][4096]
  float*          bqkv  = (float*)(ws + (88ull << 20));           // 12 KB [3072]

  dim3 blk(256);
  // weight transposes (fp32 -> bf16 W^T)
  tr_kernel<<<dim3(32, 32), blk, 0, stream>>>(Wq, WqkvT, 1024, 1024);
  tr_kernel<<<dim3(32, 32), blk, 0, stream>>>(Wk, WqkvT + 1024 * 1024, 1024, 1024);
  tr_kernel<<<dim3(32, 32), blk, 0, stream>>>(Wv, WqkvT + 2 * 1024 * 1024, 1024, 1024);
  tr_kernel<<<dim3(32, 32), blk, 0, stream>>>(Wo, WoT, 1024, 1024);
  tr_kernel<<<dim3(128, 32), blk, 0, stream>>>(Wup, WupT, 1024, 4096);
  tr_kernel<<<dim3(32, 128), blk, 0, stream>>>(Wdn, WdnT, 4096, 1024);
  concat3_kernel<<<dim3(4), blk, 0, stream>>>(bq, bk, bv, bqkv, 1024);

  // x -> rmsnorm -> qkv
  rmsnorm_kernel<<<dim3(NROW), blk, 0, stream>>>(x, ln1w, xn1);
  gemm_bt<0><<<dim3(24, 32), blk, 0, stream>>>(xn1, WqkvT, bqkv, nullptr, qkv, NROW, 3072, 1024);

  // V transpose then attention
  vtr_kernel<<<dim3(32, 32), blk, 0, stream>>>(qkv, vtb);
  attn_kernel<<<dim3(512), blk, 0, stream>>>(qkv, vtb, attn);

  // x2 = x + attn @ Wo + bo
  gemm_bt<1><<<dim3(8, 32), blk, 0, stream>>>(attn, WoT, bo, x, x2, NROW, 1024, 1024);

  // mlp
  rmsnorm_kernel<<<dim3(NROW), blk, 0, stream>>>(x2, ln2w, h2);
  gemm_bt<2><<<dim3(32, 32), blk, 0, stream>>>(h2, WupT, bup, nullptr, gbuf, NROW, 4096, 1024);
  gemm_bt<1><<<dim3(8, 32), blk, 0, stream>>>(gbuf, WdnT, bdn, x2, d_out, NROW, 1024, 4096);
}

// Round 5
// 491.373 us; speedup vs baseline: 1.1995x; 1.0025x over previous
//
#include <hip/hip_runtime.h>
#include <cmath>

#define DM   1024
#define HDS  16
#define DH   64
#define DMLP 4096
#define TSEQ 2048
#define NROW 4096   // B*T = 2*2048

typedef short bf16x8 __attribute__((ext_vector_type(8)));
typedef float f32x4 __attribute__((ext_vector_type(4)));

__device__ __forceinline__ unsigned short f2bf(float f) {
  union { float f; unsigned u; } v; v.f = f;
  unsigned r = v.u + 0x7fffu + ((v.u >> 16) & 1u);
  return (unsigned short)(r >> 16);
}

__device__ __forceinline__ void gload_lds16(const void* g, void* l) {
  __builtin_amdgcn_global_load_lds(
      (const __attribute__((address_space(1))) unsigned int*)g,
      (__attribute__((address_space(3))) unsigned int*)l, 16, 0, 0);
}

// ---------- transpose fp32 [K][N] -> bf16 [N][K] ----------
__global__ __launch_bounds__(256) void tr_kernel(const float* __restrict__ in,
                                                 unsigned short* __restrict__ out,
                                                 int K, int N) {
  __shared__ unsigned short tile[32][33];
  int n0 = blockIdx.x * 32, k0 = blockIdx.y * 32;
  int tx = threadIdx.x & 31, ty = threadIdx.x >> 5;
#pragma unroll
  for (int j = 0; j < 4; ++j) {
    int k = ty + j * 8;
    tile[k][tx] = f2bf(in[(size_t)(k0 + k) * N + n0 + tx]);
  }
  __syncthreads();
#pragma unroll
  for (int j = 0; j < 4; ++j) {
    int n = ty + j * 8;
    out[(size_t)(n0 + n) * K + k0 + tx] = tile[tx][n];
  }
}

__global__ void concat3_kernel(const float* __restrict__ a, const float* __restrict__ b,
                               const float* __restrict__ c, float* __restrict__ out, int n) {
  int i = blockIdx.x * 256 + threadIdx.x;
  if (i < n) { out[i] = a[i]; out[n + i] = b[i]; out[2 * n + i] = c[i]; }
}

// ---------- rmsnorm fp32 [NROW][DM] -> bf16 ----------
__global__ __launch_bounds__(256) void rmsnorm_kernel(const float* __restrict__ x,
                                                      const float* __restrict__ w,
                                                      unsigned short* __restrict__ out) {
  int row = blockIdx.x;
  int t = threadIdx.x;
  const float4* xr = (const float4*)(x + (size_t)row * DM);
  float4 v = xr[t];
  float ss = v.x * v.x + v.y * v.y + v.z * v.z + v.w * v.w;
#pragma unroll
  for (int m = 1; m < 64; m <<= 1) ss += __shfl_xor(ss, m, 64);
  __shared__ float sred[4];
  if ((t & 63) == 0) sred[t >> 6] = ss;
  __syncthreads();
  ss = sred[0] + sred[1] + sred[2] + sred[3];
  float norm = rsqrtf(ss * (1.0f / DM) + 1e-6f);
  float4 wv = ((const float4*)w)[t];
  ushort4 o;
  o.x = f2bf(v.x * norm * wv.x);
  o.y = f2bf(v.y * norm * wv.y);
  o.z = f2bf(v.z * norm * wv.z);
  o.w = f2bf(v.w * norm * wv.w);
  ((ushort4*)out)[(size_t)row * (DM / 4) + t] = o;
}

// ---------- GEMM: C[M][N] = A[M][K] * BT[N][K]^T + epilogue ----------
// EPI: 0 = +bias -> bf16 ; 1 = +bias + res -> f32 ; 2 = +bias, exact gelu -> bf16
// XCD-bijective blockIdx swizzle (T1): requires gridDim.x*gridDim.y % 8 == 0.
template <int EPI>
__global__ __launch_bounds__(256) void gemm_bt(const unsigned short* __restrict__ A,
                                               const unsigned short* __restrict__ BT,
                                               const float* __restrict__ bias,
                                               const float* __restrict__ res,
                                               void* __restrict__ outp,
                                               int M, int N, int K) {
  __shared__ alignas(16) unsigned short As[128 * 32];
  __shared__ alignas(16) unsigned short Bs[128 * 32];
  int tid = threadIdx.x;
  int w = tid >> 6, l = tid & 63;
  unsigned nx = gridDim.x;
  unsigned bidl = blockIdx.y * nx + blockIdx.x;
  unsigned nwg = nx * gridDim.y;
  unsigned cpx = nwg >> 3;
  unsigned sb = (bidl & 7) * cpx + (bidl >> 3);
  int m0 = (int)(sb / nx) * 128, n0 = (int)(sb % nx) * 128;
  int wr = w >> 1, wc = w & 1;
  f32x4 acc[4][4];
#pragma unroll
  for (int i = 0; i < 4; ++i)
#pragma unroll
    for (int j = 0; j < 4; ++j)
#pragma unroll
      for (int e = 0; e < 4; ++e) acc[i][j][e] = 0.0f;

  int nk = K >> 5;
  int arow = tid >> 2, aslot = tid & 3;  // 64 rows per half-tile, 4x16B slots per row
  for (int kt = 0; kt < nk; ++kt) {
    __syncthreads();
#pragma unroll
    for (int i = 0; i < 2; ++i) {
      int row = i * 64 + arow;
      gload_lds16(A + (size_t)(m0 + row) * K + (size_t)kt * 32 + aslot * 8,
                  (char*)As + i * 4096 + w * 1024);
      gload_lds16(BT + (size_t)(n0 + row) * K + (size_t)kt * 32 + aslot * 8,
                  (char*)Bs + i * 4096 + w * 1024);
    }
    __syncthreads();
    bf16x8 af[4], bfr[4];
#pragma unroll
    for (int mt = 0; mt < 4; ++mt)
      af[mt] = *(const bf16x8*)((const char*)As +
                (size_t)(wr * 64 + mt * 16 + (l & 15)) * 64 + (l >> 4) * 16);
#pragma unroll
    for (int nt = 0; nt < 4; ++nt)
      bfr[nt] = *(const bf16x8*)((const char*)Bs +
                 (size_t)(wc * 64 + nt * 16 + (l & 15)) * 64 + (l >> 4) * 16);
#pragma unroll
    for (int mt = 0; mt < 4; ++mt)
#pragma unroll
      for (int nt = 0; nt < 4; ++nt)
        acc[mt][nt] = __builtin_amdgcn_mfma_f32_16x16x32_bf16(af[mt], bfr[nt], acc[mt][nt], 0, 0, 0);
  }

  int g = l >> 4, c = l & 15;
#pragma unroll
  for (int mt = 0; mt < 4; ++mt) {
#pragma unroll
    for (int nt = 0; nt < 4; ++nt) {
#pragma unroll
      for (int r = 0; r < 4; ++r) {
        int m = m0 + wr * 64 + mt * 16 + g * 4 + r;
        int n = n0 + wc * 64 + nt * 16 + c;
        float v = acc[mt][nt][r] + bias[n];
        if (EPI == 2) v = 0.5f * v * (1.0f + erff(v * 0.70710678118654752f));
        if (EPI == 1) {
          v += res[(size_t)m * N + n];
          ((float*)outp)[(size_t)m * N + n] = v;
        } else {
          ((unsigned short*)outp)[(size_t)m * N + n] = f2bf(v);
        }
      }
    }
  }
}

// ---------- V transpose: qkv v-part -> VT [bh][64 d][2048 t] bf16 ----------
__global__ __launch_bounds__(256) void vtr_kernel(const unsigned short* __restrict__ qkv,
                                                  unsigned short* __restrict__ vt) {
  __shared__ unsigned short tile[64][72];
  int bh = blockIdx.y, t0 = blockIdx.x * 64;
  int b = bh >> 4, h = bh & 15;
  int r = threadIdx.x >> 3, sl = threadIdx.x & 7;
#pragma unroll
  for (int half = 0; half < 2; ++half) {
    int rr = r + half * 32;
    bf16x8 v = *(const bf16x8*)(qkv + (size_t)(b * TSEQ + t0 + rr) * 3072 + 2048 + h * 64 + sl * 8);
    *(bf16x8*)&tile[rr][sl * 8] = v;  // row stride 144B (16B-aligned)
  }
  __syncthreads();
#pragma unroll
  for (int half = 0; half < 2; ++half) {
    int d = r + half * 32;
    bf16x8 o;
#pragma unroll
    for (int j = 0; j < 8; ++j) o[j] = (short)tile[sl * 8 + j][d];
    *(bf16x8*)(vt + ((size_t)bh * 64 + d) * TSEQ + t0 + sl * 8) = o;
  }
}

// ---------- causal flash attention v4 ----------
// R2-proven template, geometry changed to 4 waves x 16 q-rows = 64 q/block.
// KVBLK=64; swizzled LDS; full online-softmax every tile (no defer, no setprio);
// deferred final l-reduce; double-buffered reg staging.
__global__ __launch_bounds__(256) void attn_kernel(const unsigned short* __restrict__ qkv,
                                                   const unsigned short* __restrict__ vt,
                                                   unsigned short* __restrict__ attn_out) {
  __shared__ alignas(16) unsigned short Ks[2][64 * 64];  // [k][d] swz
  __shared__ alignas(16) unsigned short Vs[2][64 * 64];  // [d][k] swz
  __shared__ alignas(16) unsigned short Ps[4][16 * 64];  // per-wave [q][k] swz
  int tid = threadIdx.x, w = tid >> 6, l = tid & 63, g = l >> 4, c = l & 15;
  int bid = blockIdx.x;
  int qb = 31 - (bid & 31);             // heavy blocks dispatch first
  int bh = bid >> 5, b = bh >> 4, h = bh & 15;
  int q0 = qb * 64;
  int qw = q0 + w * 16;

  // Q fragments: rows qw + c, d-slices s*32 + g*8
  bf16x8 qf[2];
#pragma unroll
  for (int s = 0; s < 2; ++s)
    qf[s] = *(const bf16x8*)(qkv + (size_t)(b * TSEQ + qw + c) * 3072 + h * 64 + s * 32 + g * 8);

  f32x4 o[4];
  float mrow[4], lpart[4];
#pragma unroll
  for (int dc = 0; dc < 4; ++dc)
#pragma unroll
    for (int e = 0; e < 4; ++e) o[dc][e] = 0.0f;
#pragma unroll
  for (int r = 0; r < 4; ++r) { mrow[r] = -1e30f; lpart[r] = 0.0f; }

  int ntile = qb + 1;
  int sr = tid >> 3, ss = tid & 7;  // staging: 32 rows x 8 slots, 2 halves
  bf16x8 kreg[2], vreg[2];

#define LOADT(K0)                                                                       \
  {                                                                                     \
    _Pragma("unroll") for (int hf = 0; hf < 2; ++hf) {                                  \
      int rr = sr + hf * 32;                                                            \
      kreg[hf] = *(const bf16x8*)(qkv + (size_t)(b * TSEQ + (K0) + rr) * 3072 + 1024 +  \
                                  h * 64 + ss * 8);                                     \
      vreg[hf] = *(const bf16x8*)(vt + ((size_t)bh * 64 + rr) * TSEQ + (K0) + ss * 8);  \
    }                                                                                   \
  }
#define WRITET(BUF)                                                                     \
  {                                                                                     \
    _Pragma("unroll") for (int hf = 0; hf < 2; ++hf) {                                  \
      int rr = sr + hf * 32;                                                            \
      unsigned off = (unsigned)(rr * 128 + ss * 16) ^ (unsigned)((rr & 7) << 4);        \
      *(bf16x8*)((char*)Ks[BUF] + off) = kreg[hf];                                      \
      *(bf16x8*)((char*)Vs[BUF] + off) = vreg[hf];                                      \
    }                                                                                   \
  }

  LOADT(0);
  WRITET(0);
  __syncthreads();

  for (int t = 0; t < ntile; ++t) {
    int k0 = t << 6, cur = t & 1;
    if (t + 1 < ntile) LOADT((t + 1) << 6);

    {
      const char* Kb = (const char*)Ks[cur];
      const char* Vb = (const char*)Vs[cur];
      // S[4ni] = Q x K^T over d=64 (2 mfma steps each)
      f32x4 s[4];
#pragma unroll
      for (int ni = 0; ni < 4; ++ni) {
        int krow = ni * 16 + c;
        unsigned swz = (unsigned)((c & 7) << 4);
        bf16x8 kf0 = *(const bf16x8*)(Kb + (((unsigned)(krow * 128) + g * 16) ^ swz));
        bf16x8 kf1 = *(const bf16x8*)(Kb + (((unsigned)(krow * 128) + 64 + g * 16) ^ swz));
        f32x4 acc;
#pragma unroll
        for (int e = 0; e < 4; ++e) acc[e] = 0.0f;
        acc = __builtin_amdgcn_mfma_f32_16x16x32_bf16(qf[0], kf0, acc, 0, 0, 0);
        acc = __builtin_amdgcn_mfma_f32_16x16x32_bf16(qf[1], kf1, acc, 0, 0, 0);
        s[ni] = acc;
      }
      bool full = (k0 + 63 <= qw);  // no masking needed for any row of this wave
#pragma unroll
      for (int r = 0; r < 4; ++r) {
        int qg = qw + g * 4 + r;
        float pm[4];
#pragma unroll
        for (int ni = 0; ni < 4; ++ni) {
          float v = s[ni][r] * 0.125f;
          if (!full) {
            int kg = k0 + ni * 16 + c;
            v = (kg <= qg) ? v : -1e30f;
          }
          pm[ni] = v;
        }
        float mx = fmaxf(fmaxf(pm[0], pm[1]), fmaxf(pm[2], pm[3]));
        mx = fmaxf(mx, __shfl_xor(mx, 1, 64));
        mx = fmaxf(mx, __shfl_xor(mx, 2, 64));
        mx = fmaxf(mx, __shfl_xor(mx, 4, 64));
        mx = fmaxf(mx, __shfl_xor(mx, 8, 64));
        float mnew = fmaxf(mrow[r], mx);
        float scale = __expf(mrow[r] - mnew);
        mrow[r] = mnew;
        float p[4], rs = 0.0f;
#pragma unroll
        for (int ni = 0; ni < 4; ++ni) { p[ni] = __expf(pm[ni] - mnew); rs += p[ni]; }
        lpart[r] = lpart[r] * scale + rs;
#pragma unroll
        for (int dc = 0; dc < 4; ++dc) o[dc][r] *= scale;
        int prow = g * 4 + r;
        unsigned pswz = (unsigned)((prow & 7) << 4);
#pragma unroll
        for (int ni = 0; ni < 4; ++ni)
          *(unsigned short*)((char*)Ps[w] +
                             (((unsigned)(prow * 128 + (ni * 16 + c) * 2)) ^ pswz)) = f2bf(p[ni]);
      }
      asm volatile("s_waitcnt lgkmcnt(0)" ::: "memory");
      // PV: O[16q][64d] += P[16q][64k] x V[64k][64d]
      unsigned swz = (unsigned)((c & 7) << 4);
#pragma unroll
      for (int kc = 0; kc < 2; ++kc) {
        bf16x8 pf = *(const bf16x8*)((const char*)Ps[w] +
                     (((unsigned)(c * 128 + kc * 64 + g * 16)) ^ swz));
#pragma unroll
        for (int dc = 0; dc < 4; ++dc) {
          bf16x8 vf = *(const bf16x8*)(Vb +
                       (((unsigned)((dc * 16 + c) * 128 + kc * 64 + g * 16)) ^ swz));
          o[dc] = __builtin_amdgcn_mfma_f32_16x16x32_bf16(pf, vf, o[dc], 0, 0, 0);
        }
      }
    }

    if (t + 1 < ntile) {
      WRITET(cur ^ 1);
      __syncthreads();
    }
  }

#pragma unroll
  for (int r = 0; r < 4; ++r) {
    float lr = lpart[r];
    lr += __shfl_xor(lr, 1, 64);
    lr += __shfl_xor(lr, 2, 64);
    lr += __shfl_xor(lr, 4, 64);
    lr += __shfl_xor(lr, 8, 64);
    float inv = 1.0f / lr;
    size_t row = (size_t)b * TSEQ + qw + g * 4 + r;
    unsigned short* op = attn_out + row * 1024 + h * 64 + c;
#pragma unroll
    for (int dc = 0; dc < 4; ++dc) op[dc * 16] = f2bf(o[dc][r] * inv);
  }
#undef LOADT
#undef WRITET
}

extern "C" void kernel_launch(void* const* d_in, const int* in_sizes, int n_in,
                              void* d_out, int out_size, void* d_ws, size_t ws_size,
                              hipStream_t stream) {
  const float* x    = (const float*)d_in[0];
  const float* ln1w = (const float*)d_in[1];
  const float* ln2w = (const float*)d_in[2];
  const float* Wq   = (const float*)d_in[3];
  const float* bq   = (const float*)d_in[4];
  const float* Wk   = (const float*)d_in[5];
  const float* bk   = (const float*)d_in[6];
  const float* Wv   = (const float*)d_in[7];
  const float* bv   = (const float*)d_in[8];
  const float* Wo   = (const float*)d_in[9];
  const float* bo   = (const float*)d_in[10];
  const float* Wup  = (const float*)d_in[11];
  const float* bup  = (const float*)d_in[12];
  const float* Wdn  = (const float*)d_in[13];
  const float* bdn  = (const float*)d_in[14];

  char* ws = (char*)d_ws;
  unsigned short* xn1   = (unsigned short*)(ws + 0);              // 8 MB [4096][1024] bf16
  unsigned short* vtb   = (unsigned short*)(ws + 0);              // 8 MB [32][64][2048] bf16 (aliases xn1, dead by then)
  unsigned short* qkv   = (unsigned short*)(ws + (8ull << 20));   // 24 MB [4096][3072] bf16
  unsigned short* gbuf  = (unsigned short*)(ws + 0);              // 32 MB, aliases vtb+qkv (both dead)
  unsigned short* attn  = (unsigned short*)(ws + (32ull << 20));  // 8 MB [4096][1024] bf16
  float*          x2    = (float*)(ws + (40ull << 20));           // 16 MB [4096][1024] f32
  unsigned short* h2    = (unsigned short*)(ws + (56ull << 20));  // 8 MB
  unsigned short* WqkvT = (unsigned short*)(ws + (64ull << 20));  // 6 MB [3072][1024]
  unsigned short* WoT   = (unsigned short*)(ws + (70ull << 20));  // 2 MB [1024][1024]
  unsigned short* WupT  = (unsigned short*)(ws + (72ull << 20));  // 8 MB [4096][1024]
  unsigned short* WdnT  = (unsigned short*)(ws + (80ull << 20));  // 8 MB [1024][4096]
  float*          bqkv  = (float*)(ws + (88ull << 20));           // 12 KB [3072]

  dim3 blk(256);
  // weight transposes (fp32 -> bf16 W^T)
  tr_kernel<<<dim3(32, 32), blk, 0, stream>>>(Wq, WqkvT, 1024, 1024);
  tr_kernel<<<dim3(32, 32), blk, 0, stream>>>(Wk, WqkvT + 1024 * 1024, 1024, 1024);
  tr_kernel<<<dim3(32, 32), blk, 0, stream>>>(Wv, WqkvT + 2 * 1024 * 1024, 1024, 1024);
  tr_kernel<<<dim3(32, 32), blk, 0, stream>>>(Wo, WoT, 1024, 1024);
  tr_kernel<<<dim3(128, 32), blk, 0, stream>>>(Wup, WupT, 1024, 4096);
  tr_kernel<<<dim3(32, 128), blk, 0, stream>>>(Wdn, WdnT, 4096, 1024);
  concat3_kernel<<<dim3(4), blk, 0, stream>>>(bq, bk, bv, bqkv, 1024);

  // x -> rmsnorm -> qkv
  rmsnorm_kernel<<<dim3(NROW), blk, 0, stream>>>(x, ln1w, xn1);
  gemm_bt<0><<<dim3(24, 32), blk, 0, stream>>>(xn1, WqkvT, bqkv, nullptr, qkv, NROW, 3072, 1024);

  // V transpose then attention
  vtr_kernel<<<dim3(32, 32), blk, 0, stream>>>(qkv, vtb);
  attn_kernel<<<dim3(1024), blk, 0, stream>>>(qkv, vtb, attn);

  // x2 = x + attn @ Wo + bo
  gemm_bt<1><<<dim3(8, 32), blk, 0, stream>>>(attn, WoT, bo, x, x2, NROW, 1024, 1024);

  // mlp
  rmsnorm_kernel<<<dim3(NROW), blk, 0, stream>>>(x2, ln2w, h2);
  gemm_bt<2><<<dim3(32, 32), blk, 0, stream>>>(h2, WupT, bup, nullptr, gbuf, NROW, 4096, 1024);
  gemm_bt<1><<<dim3(8, 32), blk, 0, stream>>>(gbuf, WdnT, bdn, x2, d_out, NROW, 1024, 4096);
}